// Round 15
// baseline (123.368 us; speedup 1.0000x reference)
//
#include <hip/hip_runtime.h>
#include <hip/hip_bf16.h>
#include <stdint.h>

#define IN_FEAT 37
#define IN_CH 512
#define NUM_HEADS 8
#define DEPTH 64
#define BB 4
#define SS 2048
#define NROWS (BB * SS)

typedef unsigned short u16;
typedef __attribute__((ext_vector_type(8))) short bf16x8;
typedef __attribute__((ext_vector_type(4))) float f32x4;
typedef __attribute__((ext_vector_type(16))) float f32x16;
typedef __attribute__((ext_vector_type(4))) unsigned u32x4;

#define MFMA16(a, b, c) __builtin_amdgcn_mfma_f32_16x16x32_bf16(a, b, c, 0, 0, 0)
#define MFMA32(a, b, c) __builtin_amdgcn_mfma_f32_32x32x16_bf16(a, b, c, 0, 0, 0)

#define GLDS16(gsrc, ldst)                                                          \
    __builtin_amdgcn_global_load_lds(                                               \
        reinterpret_cast<const __attribute__((address_space(1))) void*>(            \
            reinterpret_cast<uintptr_t>(gsrc)),                                     \
        reinterpret_cast<__attribute__((address_space(3))) void*>(                  \
            reinterpret_cast<uintptr_t>(ldst)),                                     \
        16, 0, 0)

__device__ __forceinline__ u16 f2bf(float f) {
    union { float f; unsigned u; } v;
    v.f = f;
    unsigned r = v.u + 0x7fffu + ((v.u >> 16) & 1u);
    return (u16)(r >> 16);
}

// RNE pack of two f32 -> u32 of 2x bf16 (low = a, high = b).
__device__ __forceinline__ unsigned cvt_pk_bf16(float a, float b) {
    unsigned r;
    asm("v_cvt_pk_bf16_f32 %0, %1, %2" : "=v"(r) : "v"(a), "v"(b));
    return r;
}

// single-instruction 2^x
__device__ __forceinline__ float fexp2(float x) {
    float r;
    asm("v_exp_f32 %0, %1" : "=v"(r) : "v"(x));
    return r;
}

// ---------------------------------------------------------------------------
// Kernel 0: pack to bf16 MFMA-ready layouts (unchanged).
// ---------------------------------------------------------------------------
#define XB_ELEMS (NROWS * 64)
#define WT_ELEMS (IN_CH * 64)
#define WD_ELEMS (IN_CH * IN_CH)
#define PACK_TOTAL (XB_ELEMS + 3 * WT_ELEMS + WD_ELEMS)

__global__ __launch_bounds__(256) void pack_all(
    const float* __restrict__ x,
    const float* __restrict__ Wq, const float* __restrict__ Wk,
    const float* __restrict__ Wv, const float* __restrict__ Wd,
    u16* __restrict__ xb, u16* __restrict__ WqT, u16* __restrict__ WkT,
    u16* __restrict__ WvT, u16* __restrict__ WdT)
{
    const float QSC = 0.125f * 1.44269504f;
    int idx = blockIdx.x * 256 + threadIdx.x;
    if (idx < XB_ELEMS) {
        int row = idx >> 6, col = idx & 63;
        xb[idx] = (col < IN_FEAT) ? f2bf(x[row * IN_FEAT + col]) : (u16)0;
    } else if (idx < XB_ELEMS + 3 * WT_ELEMS) {
        int j = idx - XB_ELEMS;
        int mat = j >> 15, rem = j & (WT_ELEMS - 1);
        int c = rem >> 6, i = rem & 63;
        float v = 0.f;
        if (i < IN_FEAT) {
            if (mat == 0)      v = Wq[i * IN_CH + c] * QSC;
            else if (mat == 1) v = Wk[i * IN_CH + c];
            else               v = Wv[i * IN_CH + c];
        }
        (mat == 0 ? WqT : mat == 1 ? WkT : WvT)[rem] = f2bf(v);
    } else if (idx < PACK_TOTAL) {
        int j = idx - (XB_ELEMS + 3 * WT_ELEMS);
        int r = j >> 9, c = j & 511;
        WdT[c * IN_CH + r] = f2bf(Wd[j]);
    }
}

// ---------------------------------------------------------------------------
// Kernel 1: merged projection (unchanged from round 11).
// ---------------------------------------------------------------------------
__global__ __launch_bounds__(256) void proj_all(
    const u16* __restrict__ xb, const u16* __restrict__ WqT,
    const u16* __restrict__ WkT, const u16* __restrict__ WvT,
    const float* __restrict__ bqp, const float* __restrict__ bkp,
    const float* __restrict__ bvp,
    u16* __restrict__ qo, u16* __restrict__ ko, u16* __restrict__ vo)
{
    const int tid = threadIdx.x;
    const int w = tid >> 6, lane = tid & 63;
    const int g = lane >> 4, l15 = lane & 15;
    const f32x4 Z4 = {0.f, 0.f, 0.f, 0.f};

    if (blockIdx.z == 0) {
        const float QSC = 0.125f * 1.44269504f;
        const int m0 = blockIdx.x * 64 + w * 16;
        const int n0 = blockIdx.y * 64;

        f32x4 aq[4], ak[4];
#pragma unroll
        for (int nt = 0; nt < 4; ++nt) { aq[nt] = Z4; ak[nt] = Z4; }

#pragma unroll
        for (int k0 = 0; k0 < 64; k0 += 32) {
            bf16x8 a = *(const bf16x8*)&xb[(m0 + l15) * 64 + k0 + g * 8];
#pragma unroll
            for (int nt = 0; nt < 4; ++nt) {
                bf16x8 bq8 = *(const bf16x8*)&WqT[(n0 + nt * 16 + l15) * 64 + k0 + g * 8];
                bf16x8 bk8 = *(const bf16x8*)&WkT[(n0 + nt * 16 + l15) * 64 + k0 + g * 8];
                aq[nt] = MFMA16(a, bq8, aq[nt]);
                ak[nt] = MFMA16(a, bk8, ak[nt]);
            }
        }
#pragma unroll
        for (int nt = 0; nt < 4; ++nt) {
            const int n = n0 + nt * 16 + l15;
            const float bqv = bqp[n] * QSC, bkv = bkp[n];
            const int h = n >> 6, d = n & 63;
#pragma unroll
            for (int r = 0; r < 4; ++r) {
                const int m = m0 + g * 4 + r;
                const int b = m >> 11, s = m & 2047;
                const int bh = b * NUM_HEADS + h;
                qo[(bh * SS + s) * DEPTH + d] = f2bf(aq[nt][r] + bqv);
                ko[bh * (SS * 64) + (s >> 6) * 4096 + (s & 63) * 64 + (d ^ ((s & 7) << 3))] =
                    f2bf(ak[nt][r] + bkv);
            }
        }
    } else {
        const int m0 = blockIdx.y * 64 + w * 16;   // channel dim (512)
        const int n0 = blockIdx.x * 64;            // row dim (8192)

        f32x4 acc[4];
#pragma unroll
        for (int nt = 0; nt < 4; ++nt) acc[nt] = Z4;

#pragma unroll
        for (int k0 = 0; k0 < 64; k0 += 32) {
            bf16x8 a = *(const bf16x8*)&WvT[(m0 + l15) * 64 + k0 + g * 8];
#pragma unroll
            for (int nt = 0; nt < 4; ++nt) {
                bf16x8 b8 = *(const bf16x8*)&xb[(n0 + nt * 16 + l15) * 64 + k0 + g * 8];
                acc[nt] = MFMA16(a, b8, acc[nt]);
            }
        }
        float bvr[4];
#pragma unroll
        for (int r = 0; r < 4; ++r) bvr[r] = bvp[m0 + g * 4 + r];
#pragma unroll
        for (int nt = 0; nt < 4; ++nt) {
#pragma unroll
            for (int r = 0; r < 4; ++r) {
                const int c = m0 + g * 4 + r;
                const int rr = n0 + nt * 16 + l15;
                const int b = rr >> 11, s = rr & 2047;
                const int h = c >> 6, d = c & 63;
                const int bh = b * NUM_HEADS + h;
                vo[bh * (SS * 64) + (s >> 6) * 4096 + d * 64 + ((s & 63) ^ ((d & 7) << 3))] =
                    f2bf(acc[nt][r] + bvr[r]);
            }
        }
    }
}

// ---------------------------------------------------------------------------
// Kernel 3: flash attention — round-9 code (known-good: 59 µs, VGPR 60,
// absmax 0.0020) with ONE correctness-neutral addition: s_setprio(1)/(0)
// around the two MFMA clusters (T5; waves drift freely here so the CU
// scheduler has role diversity to arbitrate).
// ---------------------------------------------------------------------------
#define NT (SS / 64)

__global__ __launch_bounds__(256, 4) void attn_kernel(
    const u16* __restrict__ Qm, const u16* __restrict__ Km,
    const u16* __restrict__ Vm, u16* __restrict__ Om)
{
    __shared__ u16 KL[4][2][2048];   // [wave][buf][32 krows x 64 u16] = 32 KB
    const int tid = threadIdx.x;
    const int w = tid >> 6, lane = tid & 63;
    const int r31 = lane & 31, lh = lane >> 5;
    const int qgrp = w >> 1, kh = w & 1;

    const int lin = blockIdx.x + gridDim.x * blockIdx.y;
    const int xcd = lin & 7, t7 = lin >> 3;
    const int bx = t7 & 31, bh = xcd + 8 * (t7 >> 5);
    const int qbase = bx * 64 + qgrp * 32;

    const u16* ktg = Km + bh * (SS * 64) + kh * 2048;  // this wave's key-half rows
    const u16* vtg = Vm + bh * (SS * 64);

    // Q B-frags: lane(q=r31, lh) holds Q[q][d = c*16 + lh*8 + j]
    bf16x8 Qf[4];
#pragma unroll
    for (int c = 0; c < 4; ++c)
        Qf[c] = *(const bf16x8*)&Qm[(bh * SS + qbase + r31) * 64 + c * 16 + lh * 8];

    f32x16 O0, O1, Z16;
#pragma unroll
    for (int i = 0; i < 16; ++i) { O0[i] = 0.f; O1[i] = 0.f; Z16[i] = 0.f; }
    float lreg = 0.f;

    // wave-private K staging: 4 linear 1KB GLDS issues
    auto STAGE_K = [&](int buf, int t) {
        const u16* ks = ktg + t * 4096 + lane * 8;
        u16* kd = &KL[w][buf][0];
#pragma unroll
        for (int i = 0; i < 4; ++i) GLDS16(ks + i * 512, kd + i * 512);
    };

    STAGE_K(0, 0);
    STAGE_K(1, 1);

    for (int t = 0; t < NT; ++t) {
        if (t < NT - 1) asm volatile("s_waitcnt vmcnt(4)" ::: "memory");
        else            asm volatile("s_waitcnt vmcnt(0)" ::: "memory");
        __builtin_amdgcn_sched_barrier(0);

        // V(t) register loads (L2-resident); consumed by PV ~400cy later
        bf16x8 v[4];
        {
            const u16* vt = vtg + t * 4096;
#pragma unroll
            for (int dt = 0; dt < 2; ++dt)
#pragma unroll
                for (int o = 0; o < 2; ++o) {
                    const int vrow = dt * 32 + r31;
                    v[dt * 2 + o] = *(const bf16x8*)
                        &vt[vrow * 64 + ((kh * 32 + o * 16 + lh * 8) ^ ((vrow & 7) << 3))];
                }
        }

        // K frags from LDS
        const u16* kb = &KL[w][t & 1][0];
        bf16x8 kf[4];
#pragma unroll
        for (int c = 0; c < 4; ++c)
            kf[c] = *(const bf16x8*)&kb[r31 * 64 + ((c * 16 + lh * 8) ^ ((r31 & 7) << 3))];

        // QK^T (swapped): C[k][q]
        __builtin_amdgcn_s_setprio(1);
        f32x16 s = MFMA32(kf[0], Qf[0], Z16);
        s = MFMA32(kf[1], Qf[1], s);
        s = MFMA32(kf[2], Qf[2], s);
        s = MFMA32(kf[3], Qf[3], s);
        __builtin_amdgcn_s_setprio(0);

        // restage this buffer for t+2 (kf already consumed by MFMAs)
        if (t + 2 < NT) {
            asm volatile("s_waitcnt lgkmcnt(0)" ::: "memory");
            __builtin_amdgcn_sched_barrier(0);
            STAGE_K(t & 1, t + 2);
        }

        // raw exp2 softmax (logits bounded), pack pairs in-register
        unsigned pk[8];
        float ps = 0.f;
#pragma unroll
        for (int j = 0; j < 8; ++j) {
            float a = fexp2(s[2 * j]);
            float b = fexp2(s[2 * j + 1]);
            ps += a + b;
            pk[j] = cvt_pk_bf16(a, b);
        }
        lreg += ps;

        asm("v_permlane32_swap_b32 %0, %1" : "+v"(pk[0]), "+v"(pk[2]));
        asm("v_permlane32_swap_b32 %0, %1" : "+v"(pk[1]), "+v"(pk[3]));
        asm("v_permlane32_swap_b32 %0, %1" : "+v"(pk[4]), "+v"(pk[6]));
        asm("v_permlane32_swap_b32 %0, %1" : "+v"(pk[5]), "+v"(pk[7]));

        union { u32x4 u; bf16x8 b; } f0, f1;
        f0.u = (u32x4){pk[0], pk[1], pk[2], pk[3]};
        f1.u = (u32x4){pk[4], pk[5], pk[6], pk[7]};

        // PV (compiler auto-waits vmcnt for v regs)
        __builtin_amdgcn_s_setprio(1);
        O0 = MFMA32(f0.b, v[0], O0);
        O0 = MFMA32(f1.b, v[1], O0);
        O1 = MFMA32(f0.b, v[2], O1);
        O1 = MFMA32(f1.b, v[3], O1);
        __builtin_amdgcn_s_setprio(0);
    }

    // ---- epilogue: merge key-half pairs, normalize, store ----
    asm volatile("s_waitcnt vmcnt(0)" ::: "memory");
    __syncthreads();
    float lfull = lreg + __shfl_xor(lreg, 32, 64);
    float* sc = (float*)&KL[0][0][0];
    float* scp = sc + qgrp * 2112;
    if (kh == 1) {
#pragma unroll
        for (int i = 0; i < 16; ++i) scp[i * 64 + lane] = O0[i];
#pragma unroll
        for (int i = 0; i < 16; ++i) scp[(16 + i) * 64 + lane] = O1[i];
        scp[2048 + lane] = lfull;
    }
    __syncthreads();
    if (kh == 0) {
#pragma unroll
        for (int i = 0; i < 16; ++i) O0[i] += scp[i * 64 + lane];
#pragma unroll
        for (int i = 0; i < 16; ++i) O1[i] += scp[(16 + i) * 64 + lane];
        const float inv = 1.0f / (lfull + scp[2048 + lane]);
        const int b = bh >> 3, hh = bh & 7;
#pragma unroll
        for (int i = 0; i < 16; ++i) {
            const int qr = (i & 3) + 8 * (i >> 2) + 4 * lh;   // C-layout row
            const float invq = __shfl(inv, qr, 64);
            const int srow = qbase + qr;
            u16* orow = &Om[((b * SS + srow) << 9) + hh * 64];
            orow[r31]      = f2bf(O0[i] * invq);
            orow[32 + r31] = f2bf(O1[i] * invq);
        }
    }
}

// ---------------------------------------------------------------------------
// Kernel 4: output GEMM (unchanged).
// ---------------------------------------------------------------------------
__global__ __launch_bounds__(256) void out_gemm(
    const u16* __restrict__ A, const u16* __restrict__ BT,
    const float* __restrict__ bd, float* __restrict__ out)
{
    const int tid = threadIdx.x;
    const int w = tid >> 6, lane = tid & 63;
    const int g = lane >> 4, l15 = lane & 15;
    const int m0 = blockIdx.x * 64 + w * 16;
    const int n0 = blockIdx.y * 64;
    const f32x4 Z4 = {0.f, 0.f, 0.f, 0.f};

    f32x4 acc[4];
#pragma unroll
    for (int nt = 0; nt < 4; ++nt) acc[nt] = Z4;

    for (int k0 = 0; k0 < IN_CH; k0 += 32) {
        bf16x8 a = *(const bf16x8*)&A[(m0 + l15) * IN_CH + k0 + g * 8];
#pragma unroll
        for (int nt = 0; nt < 4; ++nt) {
            bf16x8 b = *(const bf16x8*)&BT[(n0 + nt * 16 + l15) * IN_CH + k0 + g * 8];
            acc[nt] = MFMA16(a, b, acc[nt]);
        }
    }
#pragma unroll
    for (int nt = 0; nt < 4; ++nt)
#pragma unroll
        for (int r = 0; r < 4; ++r) {
            const int m = m0 + g * 4 + r;
            const int n = n0 + nt * 16 + l15;
            out[m * IN_CH + n] = acc[nt][r] + bd[n];
        }
}

// ---------------------------------------------------------------------------
extern "C" void kernel_launch(void* const* d_in, const int* in_sizes, int n_in,
                              void* d_out, int out_size, void* d_ws, size_t ws_size,
                              hipStream_t stream)
{
    const float* x  = (const float*)d_in[0];
    const float* Wq = (const float*)d_in[1];
    const float* bq = (const float*)d_in[2];
    const float* Wk = (const float*)d_in[3];
    const float* bk = (const float*)d_in[4];
    const float* Wv = (const float*)d_in[5];
    const float* bv = (const float*)d_in[6];
    const float* Wd = (const float*)d_in[7];
    const float* bd = (const float*)d_in[8];
    float* out = (float*)d_out;

    u16* ws  = (u16*)d_ws;
    u16* q   = ws;                        // 8192*512
    u16* k   = q + NROWS * IN_CH;         // 8192*512 (swizzled tiled)
    u16* vT  = k + NROWS * IN_CH;         // 8192*512 (swizzled tiled)
    u16* ao  = vT + NROWS * IN_CH;        // 8192*512
    u16* WdT = ao + NROWS * IN_CH;        // 512*512
    u16* xb  = WdT + WD_ELEMS;            // 8192*64
    u16* WqT = xb + XB_ELEMS;             // 512*64
    u16* WkT = WqT + WT_ELEMS;            // 512*64
    u16* WvT = WkT + WT_ELEMS;            // 512*64

    pack_all<<<dim3((PACK_TOTAL + 255) / 256), dim3(256), 0, stream>>>(
        x, Wq, Wk, Wv, Wd, xb, WqT, WkT, WvT, WdT);
    proj_all<<<dim3(NROWS / 64, IN_CH / 64, 2), dim3(256), 0, stream>>>(
        xb, WqT, WkT, WvT, bq, bk, bv, q, k, vT);
    attn_kernel<<<dim3(SS / 64, BB * NUM_HEADS), dim3(256), 0, stream>>>(q, k, vT, ao);
    out_gemm<<<dim3(NROWS / 64, IN_CH / 64), dim3(256), 0, stream>>>(ao, WdT, bd, out);
}

// Round 16
// 120.971 us; speedup vs baseline: 1.0198x; 1.0198x over previous
//
#include <hip/hip_runtime.h>
#include <hip/hip_bf16.h>
#include <stdint.h>

#define IN_FEAT 37
#define IN_CH 512
#define NUM_HEADS 8
#define DEPTH 64
#define BB 4
#define SS 2048
#define NROWS (BB * SS)

typedef unsigned short u16;
typedef __attribute__((ext_vector_type(4))) unsigned short u16x4;
typedef __attribute__((ext_vector_type(8))) short bf16x8;
typedef __attribute__((ext_vector_type(4))) float f32x4;
typedef __attribute__((ext_vector_type(16))) float f32x16;
typedef __attribute__((ext_vector_type(4))) unsigned u32x4;

#define MFMA16(a, b, c) __builtin_amdgcn_mfma_f32_16x16x32_bf16(a, b, c, 0, 0, 0)
#define MFMA32(a, b, c) __builtin_amdgcn_mfma_f32_32x32x16_bf16(a, b, c, 0, 0, 0)

#define GLDS16(gsrc, ldst)                                                          \
    __builtin_amdgcn_global_load_lds(                                               \
        reinterpret_cast<const __attribute__((address_space(1))) void*>(            \
            reinterpret_cast<uintptr_t>(gsrc)),                                     \
        reinterpret_cast<__attribute__((address_space(3))) void*>(                  \
            reinterpret_cast<uintptr_t>(ldst)),                                     \
        16, 0, 0)

__device__ __forceinline__ u16 f2bf(float f) {
    union { float f; unsigned u; } v;
    v.f = f;
    unsigned r = v.u + 0x7fffu + ((v.u >> 16) & 1u);
    return (u16)(r >> 16);
}

// RNE pack of two f32 -> u32 of 2x bf16 (low = a, high = b).
__device__ __forceinline__ unsigned cvt_pk_bf16(float a, float b) {
    unsigned r;
    asm("v_cvt_pk_bf16_f32 %0, %1, %2" : "=v"(r) : "v"(a), "v"(b));
    return r;
}

// single-instruction 2^x
__device__ __forceinline__ float fexp2(float x) {
    float r;
    asm("v_exp_f32 %0, %1" : "=v"(r) : "v"(x));
    return r;
}

// ---------------------------------------------------------------------------
// Kernel 0: pack to bf16 MFMA-ready layouts (unchanged).
// ---------------------------------------------------------------------------
#define XB_ELEMS (NROWS * 64)
#define WT_ELEMS (IN_CH * 64)
#define WD_ELEMS (IN_CH * IN_CH)
#define PACK_TOTAL (XB_ELEMS + 3 * WT_ELEMS + WD_ELEMS)

__global__ __launch_bounds__(256) void pack_all(
    const float* __restrict__ x,
    const float* __restrict__ Wq, const float* __restrict__ Wk,
    const float* __restrict__ Wv, const float* __restrict__ Wd,
    u16* __restrict__ xb, u16* __restrict__ WqT, u16* __restrict__ WkT,
    u16* __restrict__ WvT, u16* __restrict__ WdT)
{
    const float QSC = 0.125f * 1.44269504f;
    int idx = blockIdx.x * 256 + threadIdx.x;
    if (idx < XB_ELEMS) {
        int row = idx >> 6, col = idx & 63;
        xb[idx] = (col < IN_FEAT) ? f2bf(x[row * IN_FEAT + col]) : (u16)0;
    } else if (idx < XB_ELEMS + 3 * WT_ELEMS) {
        int j = idx - XB_ELEMS;
        int mat = j >> 15, rem = j & (WT_ELEMS - 1);
        int c = rem >> 6, i = rem & 63;
        float v = 0.f;
        if (i < IN_FEAT) {
            if (mat == 0)      v = Wq[i * IN_CH + c] * QSC;
            else if (mat == 1) v = Wk[i * IN_CH + c];
            else               v = Wv[i * IN_CH + c];
        }
        (mat == 0 ? WqT : mat == 1 ? WkT : WvT)[rem] = f2bf(v);
    } else if (idx < PACK_TOTAL) {
        int j = idx - (XB_ELEMS + 3 * WT_ELEMS);
        int r = j >> 9, c = j & 511;
        WdT[c * IN_CH + r] = f2bf(Wd[j]);
    }
}

// ---------------------------------------------------------------------------
// Kernel 1: merged projection, round-15: operand orders swapped per output so
// every thread's 4 acc values are CONTIGUOUS in the target layout -> one
// 8-byte u16x4 store instead of 4 scalar u16 stores.
//   z=0: Q,K as C[c,s] = W @ xb^T  (thread holds 4 adjacent d, fixed s)
//   z=1: V   as C[s,c] = xb @ Wv^T (thread holds 4 adjacent s, fixed d)
// ---------------------------------------------------------------------------
__global__ __launch_bounds__(256) void proj_all(
    const u16* __restrict__ xb, const u16* __restrict__ WqT,
    const u16* __restrict__ WkT, const u16* __restrict__ WvT,
    const float* __restrict__ bqp, const float* __restrict__ bkp,
    const float* __restrict__ bvp,
    u16* __restrict__ qo, u16* __restrict__ ko, u16* __restrict__ vo)
{
    const float QSC = 0.125f * 1.44269504f;
    const int tid = threadIdx.x;
    const int w = tid >> 6, lane = tid & 63;
    const int g = lane >> 4, l15 = lane & 15;
    const f32x4 Z4 = {0.f, 0.f, 0.f, 0.f};

    if (blockIdx.z == 0) {
        // ---- Q,K: A = W rows (channels), B = xb rows (s) ----
        const int m0 = blockIdx.y * 64 + w * 16;   // channel dim (512)
        const int n0 = blockIdx.x * 64;            // row dim (8192)

        f32x4 aq[4], ak[4];
#pragma unroll
        for (int nt = 0; nt < 4; ++nt) { aq[nt] = Z4; ak[nt] = Z4; }

#pragma unroll
        for (int k0 = 0; k0 < 64; k0 += 32) {
            bf16x8 wq8 = *(const bf16x8*)&WqT[(m0 + l15) * 64 + k0 + g * 8];
            bf16x8 wk8 = *(const bf16x8*)&WkT[(m0 + l15) * 64 + k0 + g * 8];
#pragma unroll
            for (int nt = 0; nt < 4; ++nt) {
                bf16x8 b8 = *(const bf16x8*)&xb[(n0 + nt * 16 + l15) * 64 + k0 + g * 8];
                aq[nt] = MFMA16(wq8, b8, aq[nt]);
                ak[nt] = MFMA16(wk8, b8, ak[nt]);
            }
        }
        const int c0 = m0 + g * 4;                 // 4 adjacent channels
        const int h = c0 >> 6, d0 = c0 & 63;
        float bq4[4], bk4[4];
#pragma unroll
        for (int r = 0; r < 4; ++r) { bq4[r] = bqp[c0 + r] * QSC; bk4[r] = bkp[c0 + r]; }
#pragma unroll
        for (int nt = 0; nt < 4; ++nt) {
            const int rr = n0 + nt * 16 + l15;
            const int b = rr >> 11, s = rr & 2047;
            const int bh = b * NUM_HEADS + h;
            u16x4 pq, pkk;
#pragma unroll
            for (int r = 0; r < 4; ++r) {
                pq[r]  = f2bf(aq[nt][r] + bq4[r]);
                pkk[r] = f2bf(ak[nt][r] + bk4[r]);
            }
            *(u16x4*)&qo[(bh * SS + s) * DEPTH + d0] = pq;
            *(u16x4*)&ko[bh * (SS * 64) + (s >> 6) * 4096 + (s & 63) * 64 +
                          (d0 ^ ((s & 7) << 3))] = pkk;
        }
    } else {
        // ---- V: A = xb rows (s), B = Wv rows (channels) ----
        const int m0 = blockIdx.x * 64 + w * 16;   // row dim (8192)
        const int n0 = blockIdx.y * 64;            // channel dim (512)

        f32x4 acc[4];
#pragma unroll
        for (int nt = 0; nt < 4; ++nt) acc[nt] = Z4;

#pragma unroll
        for (int k0 = 0; k0 < 64; k0 += 32) {
            bf16x8 a = *(const bf16x8*)&xb[(m0 + l15) * 64 + k0 + g * 8];
#pragma unroll
            for (int nt = 0; nt < 4; ++nt) {
                bf16x8 b8 = *(const bf16x8*)&WvT[(n0 + nt * 16 + l15) * 64 + k0 + g * 8];
                acc[nt] = MFMA16(a, b8, acc[nt]);
            }
        }
        const int s0g = m0 + g * 4;                // 4 adjacent rows
        const int b = s0g >> 11, ss0 = s0g & 2047;
#pragma unroll
        for (int nt = 0; nt < 4; ++nt) {
            const int n = n0 + nt * 16 + l15;
            const int h = n >> 6, dd = n & 63;
            const int bh = b * NUM_HEADS + h;
            const float bv = bvp[n];
            u16x4 pv;
#pragma unroll
            for (int r = 0; r < 4; ++r) pv[r] = f2bf(acc[nt][r] + bv);
            *(u16x4*)&vo[bh * (SS * 64) + (ss0 >> 6) * 4096 + dd * 64 +
                          ((ss0 & 63) ^ ((dd & 7) << 3))] = pv;
        }
    }
}

// ---------------------------------------------------------------------------
// Kernel 3: flash attention — round-9 code EXACT (known-good: 59 µs, VGPR 60,
// absmax 0.0020). setprio removed (r14 A/B: -5%, hurt).
// ---------------------------------------------------------------------------
#define NT (SS / 64)

__global__ __launch_bounds__(256, 4) void attn_kernel(
    const u16* __restrict__ Qm, const u16* __restrict__ Km,
    const u16* __restrict__ Vm, u16* __restrict__ Om)
{
    __shared__ u16 KL[4][2][2048];   // [wave][buf][32 krows x 64 u16] = 32 KB
    const int tid = threadIdx.x;
    const int w = tid >> 6, lane = tid & 63;
    const int r31 = lane & 31, lh = lane >> 5;
    const int qgrp = w >> 1, kh = w & 1;

    const int lin = blockIdx.x + gridDim.x * blockIdx.y;
    const int xcd = lin & 7, t7 = lin >> 3;
    const int bx = t7 & 31, bh = xcd + 8 * (t7 >> 5);
    const int qbase = bx * 64 + qgrp * 32;

    const u16* ktg = Km + bh * (SS * 64) + kh * 2048;  // this wave's key-half rows
    const u16* vtg = Vm + bh * (SS * 64);

    // Q B-frags: lane(q=r31, lh) holds Q[q][d = c*16 + lh*8 + j]
    bf16x8 Qf[4];
#pragma unroll
    for (int c = 0; c < 4; ++c)
        Qf[c] = *(const bf16x8*)&Qm[(bh * SS + qbase + r31) * 64 + c * 16 + lh * 8];

    f32x16 O0, O1, Z16;
#pragma unroll
    for (int i = 0; i < 16; ++i) { O0[i] = 0.f; O1[i] = 0.f; Z16[i] = 0.f; }
    float lreg = 0.f;

    // wave-private K staging: 4 linear 1KB GLDS issues
    auto STAGE_K = [&](int buf, int t) {
        const u16* ks = ktg + t * 4096 + lane * 8;
        u16* kd = &KL[w][buf][0];
#pragma unroll
        for (int i = 0; i < 4; ++i) GLDS16(ks + i * 512, kd + i * 512);
    };

    STAGE_K(0, 0);
    STAGE_K(1, 1);

    for (int t = 0; t < NT; ++t) {
        if (t < NT - 1) asm volatile("s_waitcnt vmcnt(4)" ::: "memory");
        else            asm volatile("s_waitcnt vmcnt(0)" ::: "memory");
        __builtin_amdgcn_sched_barrier(0);

        // V(t) register loads (L2-resident); consumed by PV ~400cy later
        bf16x8 v[4];
        {
            const u16* vt = vtg + t * 4096;
#pragma unroll
            for (int dt = 0; dt < 2; ++dt)
#pragma unroll
                for (int o = 0; o < 2; ++o) {
                    const int vrow = dt * 32 + r31;
                    v[dt * 2 + o] = *(const bf16x8*)
                        &vt[vrow * 64 + ((kh * 32 + o * 16 + lh * 8) ^ ((vrow & 7) << 3))];
                }
        }

        // K frags from LDS
        const u16* kb = &KL[w][t & 1][0];
        bf16x8 kf[4];
#pragma unroll
        for (int c = 0; c < 4; ++c)
            kf[c] = *(const bf16x8*)&kb[r31 * 64 + ((c * 16 + lh * 8) ^ ((r31 & 7) << 3))];

        // QK^T (swapped): C[k][q]
        f32x16 s = MFMA32(kf[0], Qf[0], Z16);
        s = MFMA32(kf[1], Qf[1], s);
        s = MFMA32(kf[2], Qf[2], s);
        s = MFMA32(kf[3], Qf[3], s);

        // restage this buffer for t+2 (kf already consumed by MFMAs)
        if (t + 2 < NT) {
            asm volatile("s_waitcnt lgkmcnt(0)" ::: "memory");
            __builtin_amdgcn_sched_barrier(0);
            STAGE_K(t & 1, t + 2);
        }

        // raw exp2 softmax (logits bounded), pack pairs in-register
        unsigned pk[8];
        float ps = 0.f;
#pragma unroll
        for (int j = 0; j < 8; ++j) {
            float a = fexp2(s[2 * j]);
            float b = fexp2(s[2 * j + 1]);
            ps += a + b;
            pk[j] = cvt_pk_bf16(a, b);
        }
        lreg += ps;

        asm("v_permlane32_swap_b32 %0, %1" : "+v"(pk[0]), "+v"(pk[2]));
        asm("v_permlane32_swap_b32 %0, %1" : "+v"(pk[1]), "+v"(pk[3]));
        asm("v_permlane32_swap_b32 %0, %1" : "+v"(pk[4]), "+v"(pk[6]));
        asm("v_permlane32_swap_b32 %0, %1" : "+v"(pk[5]), "+v"(pk[7]));

        union { u32x4 u; bf16x8 b; } f0, f1;
        f0.u = (u32x4){pk[0], pk[1], pk[2], pk[3]};
        f1.u = (u32x4){pk[4], pk[5], pk[6], pk[7]};

        // PV (compiler auto-waits vmcnt for v regs)
        O0 = MFMA32(f0.b, v[0], O0);
        O0 = MFMA32(f1.b, v[1], O0);
        O1 = MFMA32(f0.b, v[2], O1);
        O1 = MFMA32(f1.b, v[3], O1);
    }

    // ---- epilogue: merge key-half pairs, normalize, store ----
    asm volatile("s_waitcnt vmcnt(0)" ::: "memory");
    __syncthreads();
    float lfull = lreg + __shfl_xor(lreg, 32, 64);
    float* sc = (float*)&KL[0][0][0];
    float* scp = sc + qgrp * 2112;
    if (kh == 1) {
#pragma unroll
        for (int i = 0; i < 16; ++i) scp[i * 64 + lane] = O0[i];
#pragma unroll
        for (int i = 0; i < 16; ++i) scp[(16 + i) * 64 + lane] = O1[i];
        scp[2048 + lane] = lfull;
    }
    __syncthreads();
    if (kh == 0) {
#pragma unroll
        for (int i = 0; i < 16; ++i) O0[i] += scp[i * 64 + lane];
#pragma unroll
        for (int i = 0; i < 16; ++i) O1[i] += scp[(16 + i) * 64 + lane];
        const float inv = 1.0f / (lfull + scp[2048 + lane]);
        const int b = bh >> 3, hh = bh & 7;
#pragma unroll
        for (int i = 0; i < 16; ++i) {
            const int qr = (i & 3) + 8 * (i >> 2) + 4 * lh;   // C-layout row
            const float invq = __shfl(inv, qr, 64);
            const int srow = qbase + qr;
            u16* orow = &Om[((b * SS + srow) << 9) + hh * 64];
            orow[r31]      = f2bf(O0[i] * invq);
            orow[32 + r31] = f2bf(O1[i] * invq);
        }
    }
}

// ---------------------------------------------------------------------------
// Kernel 4: output GEMM (unchanged).
// ---------------------------------------------------------------------------
__global__ __launch_bounds__(256) void out_gemm(
    const u16* __restrict__ A, const u16* __restrict__ BT,
    const float* __restrict__ bd, float* __restrict__ out)
{
    const int tid = threadIdx.x;
    const int w = tid >> 6, lane = tid & 63;
    const int g = lane >> 4, l15 = lane & 15;
    const int m0 = blockIdx.x * 64 + w * 16;
    const int n0 = blockIdx.y * 64;
    const f32x4 Z4 = {0.f, 0.f, 0.f, 0.f};

    f32x4 acc[4];
#pragma unroll
    for (int nt = 0; nt < 4; ++nt) acc[nt] = Z4;

    for (int k0 = 0; k0 < IN_CH; k0 += 32) {
        bf16x8 a = *(const bf16x8*)&A[(m0 + l15) * IN_CH + k0 + g * 8];
#pragma unroll
        for (int nt = 0; nt < 4; ++nt) {
            bf16x8 b = *(const bf16x8*)&BT[(n0 + nt * 16 + l15) * IN_CH + k0 + g * 8];
            acc[nt] = MFMA16(a, b, acc[nt]);
        }
    }
#pragma unroll
    for (int nt = 0; nt < 4; ++nt)
#pragma unroll
        for (int r = 0; r < 4; ++r) {
            const int m = m0 + g * 4 + r;
            const int n = n0 + nt * 16 + l15;
            out[m * IN_CH + n] = acc[nt][r] + bd[n];
        }
}

// ---------------------------------------------------------------------------
extern "C" void kernel_launch(void* const* d_in, const int* in_sizes, int n_in,
                              void* d_out, int out_size, void* d_ws, size_t ws_size,
                              hipStream_t stream)
{
    const float* x  = (const float*)d_in[0];
    const float* Wq = (const float*)d_in[1];
    const float* bq = (const float*)d_in[2];
    const float* Wk = (const float*)d_in[3];
    const float* bk = (const float*)d_in[4];
    const float* Wv = (const float*)d_in[5];
    const float* bv = (const float*)d_in[6];
    const float* Wd = (const float*)d_in[7];
    const float* bd = (const float*)d_in[8];
    float* out = (float*)d_out;

    u16* ws  = (u16*)d_ws;
    u16* q   = ws;                        // 8192*512
    u16* k   = q + NROWS * IN_CH;         // 8192*512 (swizzled tiled)
    u16* vT  = k + NROWS * IN_CH;         // 8192*512 (swizzled tiled)
    u16* ao  = vT + NROWS * IN_CH;        // 8192*512
    u16* WdT = ao + NROWS * IN_CH;        // 512*512
    u16* xb  = WdT + WD_ELEMS;            // 8192*64
    u16* WqT = xb + XB_ELEMS;             // 512*64
    u16* WkT = WqT + WT_ELEMS;            // 512*64
    u16* WvT = WkT + WT_ELEMS;            // 512*64

    pack_all<<<dim3((PACK_TOTAL + 255) / 256), dim3(256), 0, stream>>>(
        x, Wq, Wk, Wv, Wd, xb, WqT, WkT, WvT, WdT);
    proj_all<<<dim3(NROWS / 64, IN_CH / 64, 2), dim3(256), 0, stream>>>(
        xb, WqT, WkT, WvT, bq, bk, bv, q, k, vT);
    attn_kernel<<<dim3(SS / 64, BB * NUM_HEADS), dim3(256), 0, stream>>>(q, k, vT, ao);
    out_gemm<<<dim3(NROWS / 64, IN_CH / 64), dim3(256), 0, stream>>>(ao, WdT, bd, out);
}